// Round 5
// baseline (399.992 us; speedup 1.0000x reference)
//
#include <hip/hip_runtime.h>
#include <hip/hip_bf16.h>
#include <cstdint>
#include <cstddef>

#define SEQ 2048
#define DM  1024

typedef __attribute__((ext_vector_type(8))) __bf16 bf16x8;
typedef __attribute__((ext_vector_type(4))) float  f32x4;
using bf16 = __hip_bfloat16;

// ---------------------------------------------------------------- helpers
__device__ __forceinline__ void gload_lds16(const bf16* g, bf16* l) {
  __builtin_amdgcn_global_load_lds((const __attribute__((address_space(1))) void*)g,
                                   (__attribute__((address_space(3))) void*)l,
                                   16, 0, 0);
}
// counted-vmcnt waits (T4): leave newest stage in flight across the barrier
__device__ __forceinline__ void vm_wait4() { asm volatile("s_waitcnt vmcnt(4)" ::: "memory"); }
__device__ __forceinline__ void vm_wait0() { asm volatile("s_waitcnt vmcnt(0)" ::: "memory"); }
__device__ __forceinline__ void pipe_barrier() {
  __builtin_amdgcn_s_barrier();
  __builtin_amdgcn_sched_barrier(0);
}

// ---------------------------------------------------------------- transpose fp32(KxN) -> bf16(NxK)
__global__ void transpose_to_bf16(const float* __restrict__ in, bf16* __restrict__ out,
                                  int K, int N) {
  __shared__ float tile[32][33];
  const int k0 = blockIdx.y * 32, n0 = blockIdx.x * 32;
  const int tx = threadIdx.x, ty = threadIdx.y;
#pragma unroll
  for (int i = ty; i < 32; i += 8)
    tile[i][tx] = in[(size_t)(k0 + i) * N + n0 + tx];
  __syncthreads();
#pragma unroll
  for (int i = ty; i < 32; i += 8)
    out[(size_t)(n0 + i) * K + k0 + tx] = __float2bfloat16(tile[tx][i]);
}

// ---------------------------------------------------------------- layernorm fp32 row -> bf16
__global__ void ln_to_bf16(const float* __restrict__ x, const float* __restrict__ g,
                           const float* __restrict__ bt, bf16* __restrict__ out) {
  const int row = blockIdx.x;
  const float4 v = ((const float4*)(x + (size_t)row * DM))[threadIdx.x];
  float s  = v.x + v.y + v.z + v.w;
  float s2 = v.x * v.x + v.y * v.y + v.z * v.z + v.w * v.w;
#pragma unroll
  for (int o = 32; o > 0; o >>= 1) { s += __shfl_down(s, o); s2 += __shfl_down(s2, o); }
  __shared__ float red[8];
  const int wave = threadIdx.x >> 6, lane = threadIdx.x & 63;
  if (lane == 0) { red[wave] = s; red[4 + wave] = s2; }
  __syncthreads();
  s  = red[0] + red[1] + red[2] + red[3];
  s2 = red[4] + red[5] + red[6] + red[7];
  const float mu  = s * (1.f / DM);
  const float var = s2 * (1.f / DM) - mu * mu;
  const float r   = rsqrtf(var + 1e-5f);
  const float4 gv = ((const float4*)g)[threadIdx.x];
  const float4 bv = ((const float4*)bt)[threadIdx.x];
  bf16* o = out + (size_t)row * DM + threadIdx.x * 4;
  o[0] = __float2bfloat16((v.x - mu) * r * gv.x + bv.x);
  o[1] = __float2bfloat16((v.y - mu) * r * gv.y + bv.y);
  o[2] = __float2bfloat16((v.z - mu) * r * gv.z + bv.z);
  o[3] = __float2bfloat16((v.w - mu) * r * gv.w + bv.w);
}

// ---------------------------------------------------------------- GEMM: C = A(MxK) @ Bt(NxK)^T + bias
// 128x128 tiles, BK=32, 3-buffer depth-2 counted-vmcnt pipeline: stage tile
// t+2 each iter, wait vmcnt(4) (tile t done, tile t+1 in flight ACROSS the
// barrier). Replaces the drain-to-0 __syncthreads that cost ~2000 cy/iter.
enum { EP_BF16 = 0, EP_GELU = 1, EP_RESID = 2, EP_QKV = 3 };

template <int MODE, int TM, int TN>
__global__ __launch_bounds__(256, 3)
void gemm_bt(const bf16* __restrict__ A, const bf16* __restrict__ Bt,
             const float* __restrict__ bias, const float* __restrict__ resid,
             float* __restrict__ Cf, bf16* __restrict__ Cb, bf16* __restrict__ vt,
             int M, int N, int K) {
  constexpr int ABUF = TM * 32;
  constexpr int BBUF = TN * 32;
  constexpr int MI = TM / 32;
  constexpr int NI = TN / 32;
  __shared__ __attribute__((aligned(16))) bf16 As[3 * ABUF];
  __shared__ __attribute__((aligned(16))) bf16 Bs[3 * BBUF];
  const int tid  = threadIdx.x;
  const int wave = tid >> 6, lane = tid & 63;
  const int l16 = lane & 15, lq = lane >> 4;
  const int m0 = blockIdx.x * TM, n0 = blockIdx.y * TN;
  const int wr = (wave >> 1) * (TM / 2), wc = (wave & 1) * (TN / 2);

  f32x4 acc[MI][NI];
#pragma unroll
  for (int i = 0; i < MI; i++)
#pragma unroll
    for (int j = 0; j < NI; j++) acc[i][j] = 0;

  const int srow = tid >> 2;
  const int scol = (tid & 3) * 8;
  const bf16* ga = A  + (size_t)(m0 + srow) * K + scol;
  const bf16* gb = Bt + (size_t)(n0 + srow) * K + scol;

  auto stage = [&](int t, int buf) {
    const int kt = t << 5;
    bf16* la = As + buf * ABUF + wave * 512;
    bf16* lb = Bs + buf * BBUF + wave * 512;
    gload_lds16(ga + kt, la);
    if (TM == 128) gload_lds16(ga + (size_t)64 * K + kt, la + 2048);
    gload_lds16(gb + kt, lb);
    if (TN == 128) gload_lds16(gb + (size_t)64 * K + kt, lb + 2048);
  };

  const int NKT = K >> 5;
  stage(0, 0);
  if (NKT > 1) stage(1, 1);

  int bc = 0, bs = 2;
  for (int it = 0; it < NKT; ++it) {
    // tile 'it' must be resident; tile it+1 stays in flight
    if (it + 1 < NKT) vm_wait4(); else vm_wait0();
    pipe_barrier();
    if (it + 2 < NKT) stage(it + 2, bs);

    bf16x8 af[MI], bfr[NI];
#pragma unroll
    for (int mi = 0; mi < MI; mi++)
      af[mi] = *(const bf16x8*)(As + bc * ABUF + (wr + mi * 16 + l16) * 32 + lq * 8);
#pragma unroll
    for (int ni = 0; ni < NI; ni++)
      bfr[ni] = *(const bf16x8*)(Bs + bc * BBUF + (wc + ni * 16 + l16) * 32 + lq * 8);
#pragma unroll
    for (int mi = 0; mi < MI; mi++)
#pragma unroll
      for (int ni = 0; ni < NI; ni++)
        acc[mi][ni] = __builtin_amdgcn_mfma_f32_16x16x32_bf16(af[mi], bfr[ni], acc[mi][ni], 0, 0, 0);

    bc = (bc == 2) ? 0 : bc + 1;
    bs = (bs == 2) ? 0 : bs + 1;
  }

#pragma unroll
  for (int ni = 0; ni < NI; ni++) {
    const int col = n0 + wc + ni * 16 + l16;
    const float bb = bias[col];
#pragma unroll
    for (int mi = 0; mi < MI; mi++) {
      if constexpr (MODE == EP_QKV) {
        const int row0 = m0 + wr + mi * 16 + lq * 4;
        if (col >= 2048) {
          // V part: write transposed vt[b][hd][t], 4 contiguous t per lane
          __attribute__((aligned(8))) bf16 pk[4];
#pragma unroll
          for (int r = 0; r < 4; r++) pk[r] = __float2bfloat16(acc[mi][ni][r] + bb);
          *(uint2*)(vt + (size_t)((row0 >> 11) * 1024 + (col - 2048)) * SEQ + (row0 & 2047)) =
              *(const uint2*)pk;
        } else {
#pragma unroll
          for (int r = 0; r < 4; r++)
            Cb[(size_t)(row0 + r) * N + col] = __float2bfloat16(acc[mi][ni][r] + bb);
        }
      } else {
#pragma unroll
        for (int r = 0; r < 4; r++) {
          const int row = m0 + wr + mi * 16 + lq * 4 + r;
          const size_t idx = (size_t)row * N + col;
          float v = acc[mi][ni][r] + bb;
          if (MODE == EP_BF16) {
            Cb[idx] = __float2bfloat16(v);
          } else if (MODE == EP_GELU) {
            v = 0.5f * v * (1.0f + erff(v * 0.70710678118654752f));
            Cb[idx] = __float2bfloat16(v);
          } else {
            Cf[idx] = resid[idx] + v;
          }
        }
      }
    }
  }
}

// ---------------------------------------------------------------- thin-N GEMM: 64x64 tile, BK=64
// Same counted-vmcnt 3-buffer depth-2 pipeline; XOR-swizzled LDS (linear
// gload_lds dest + pre-swizzled global source + same XOR on ds_read_b128).
__global__ __launch_bounds__(256, 3)
void gemm_bt64(const bf16* __restrict__ A, const bf16* __restrict__ Bt,
               const float* __restrict__ bias, const float* __restrict__ resid,
               float* __restrict__ Cf, int M, int N, int K) {
  constexpr int TILE = 64 * 64;  // 4096 elems = 8KB per buffer
  __shared__ __attribute__((aligned(16))) bf16 As[3 * TILE];
  __shared__ __attribute__((aligned(16))) bf16 Bs[3 * TILE];
  const int tid  = threadIdx.x;
  const int wave = tid >> 6, lane = tid & 63;
  const int l16 = lane & 15, lq = lane >> 4;
  const int m0 = blockIdx.x * 64, n0 = blockIdx.y * 64;
  const int wr = (wave >> 1) * 32, wc = (wave & 1) * 32;

  f32x4 acc[2][2];
#pragma unroll
  for (int i = 0; i < 2; i++)
#pragma unroll
    for (int j = 0; j < 2; j++) acc[i][j] = 0;

  const int srow = tid >> 3;                // 0..31 (pass0); +32 pass1
  const int scb  = (tid & 7) ^ (srow & 7);  // (srow+32)&7 == srow&7
  const bf16* ga0 = A  + (size_t)(m0 + srow) * K + scb * 8;
  const bf16* ga1 = A  + (size_t)(m0 + srow + 32) * K + scb * 8;
  const bf16* gb0 = Bt + (size_t)(n0 + srow) * K + scb * 8;
  const bf16* gb1 = Bt + (size_t)(n0 + srow + 32) * K + scb * 8;
  const int ld0 = wave * 512;        // wave-uniform LDS dest (elems)
  const int ld1 = 2048 + wave * 512;

  auto stage = [&](int t, int buf) {
    const int kt = t << 6;
    gload_lds16(ga0 + kt, As + buf * TILE + ld0);
    gload_lds16(ga1 + kt, As + buf * TILE + ld1);
    gload_lds16(gb0 + kt, Bs + buf * TILE + ld0);
    gload_lds16(gb1 + kt, Bs + buf * TILE + ld1);
  };

  const int sxa = l16 & 7;

  const int NKT = K >> 6;
  stage(0, 0);
  if (NKT > 1) stage(1, 1);

  int bc = 0, bs = 2;
  for (int it = 0; it < NKT; ++it) {
    if (it + 1 < NKT) vm_wait4(); else vm_wait0();
    pipe_barrier();
    if (it + 2 < NKT) stage(it + 2, bs);

    const int cur = bc * TILE;
    bf16x8 af[2][2], bfv[2][2];
#pragma unroll
    for (int mi = 0; mi < 2; mi++) {
      const int row = wr + mi * 16 + l16;
#pragma unroll
      for (int kk = 0; kk < 2; kk++)
        af[mi][kk] = *(const bf16x8*)(As + cur + row * 64 + (((kk * 4 + lq) ^ sxa) << 3));
    }
#pragma unroll
    for (int ni = 0; ni < 2; ni++) {
      const int row = wc + ni * 16 + l16;
#pragma unroll
      for (int kk = 0; kk < 2; kk++)
        bfv[ni][kk] = *(const bf16x8*)(Bs + cur + row * 64 + (((kk * 4 + lq) ^ sxa) << 3));
    }
#pragma unroll
    for (int kk = 0; kk < 2; kk++)
#pragma unroll
      for (int mi = 0; mi < 2; mi++)
#pragma unroll
        for (int ni = 0; ni < 2; ni++)
          acc[mi][ni] = __builtin_amdgcn_mfma_f32_16x16x32_bf16(af[mi][kk], bfv[ni][kk],
                                                                acc[mi][ni], 0, 0, 0);

    bc = (bc == 2) ? 0 : bc + 1;
    bs = (bs == 2) ? 0 : bs + 1;
  }

#pragma unroll
  for (int ni = 0; ni < 2; ni++) {
    const int col = n0 + wc + ni * 16 + l16;
    const float bb = bias[col];
#pragma unroll
    for (int mi = 0; mi < 2; mi++) {
#pragma unroll
      for (int r = 0; r < 4; r++) {
        const int row = m0 + wr + mi * 16 + lq * 4 + r;
        const size_t idx = (size_t)row * N + col;
        Cf[idx] = resid[idx] + acc[mi][ni][r] + bb;
      }
    }
  }
}

// ---------------------------------------------------------------- flash attention v5 (causal, pair-shared)
// One 512-thread block = q-block PAIR (p, 31-p) of the same (b,h): waves 0-3
// own q-high=31-p, waves 4-7 own q-low=p. K/V tiles staged ONCE per kb and
// consumed by both halves. Constant per-CU iteration count via complementary
// pairing (id bit 8 flips p).
#define SCALE_LOG2 0.18033688011112042f  /* 0.125 * log2(e) */

__global__ __launch_bounds__(512, 2)
void flash_attn(const bf16* __restrict__ qkv, const bf16* __restrict__ VTg,
                bf16* __restrict__ out) {
  const int idx  = blockIdx.x;
  const int praw = idx & 15;
  const int p    = ((idx >> 8) & 1) ? (15 - praw) : praw;
  const int bh   = (idx >> 4) & 31;
  const int h    = bh & 15;
  const int b    = bh >> 4;
  const int qlow = p, qhigh = 31 - p;

  const int tid = threadIdx.x;
  const int w = tid >> 6, lane = tid & 63;
  const int wq = w & 3, hf = w >> 2;  // hf=0 -> qhigh, hf=1 -> qlow
  const int l16 = lane & 15, lq = lane >> 4;
  const int myqb = hf ? qlow : qhigh;

  const size_t base = (size_t)b * SEQ * 3072;
  const bf16* Qg = qkv + base + (size_t)h * 64;
  const bf16* Kg = qkv + base + 1024 + (size_t)h * 64;
  const bf16* Vt = VTg + (size_t)(b * 1024 + h * 64) * SEQ;  // [d][t] rows

  __shared__ __attribute__((aligned(16))) bf16 Ks[2 * 4096];
  __shared__ __attribute__((aligned(16))) bf16 VTs[2 * 4096];
  __shared__ __attribute__((aligned(16))) bf16 Ps[8 * 1024];

  // staging geometry: 512 threads cover a full 64x64 tile in one pass;
  // linear LDS dest (tid*16B) <-> pre-swizzled global col-block
  const int srow = tid >> 3;                 // 0..63
  const int scb  = (tid & 7) ^ (srow & 7);
  const bf16* gK = Kg + (size_t)srow * 3072 + scb * 8;
  const bf16* gV = Vt + (size_t)srow * SEQ + scb * 8;
  const int ldst = w * 512;                  // wave-uniform LDS dest (elems)

  // stage tile 0 -> buffer 0
  gload_lds16(gK, Ks + ldst);
  gload_lds16(gV, VTs + ldst);

  // Q fragments direct from global (own half's q-block)
  const bf16* qrow = Qg + (size_t)(myqb * 64 + wq * 16 + l16) * 3072 + lq * 8;
  const bf16x8 qf0 = *(const bf16x8*)(qrow);
  const bf16x8 qf1 = *(const bf16x8*)(qrow + 32);

  // swizzled frag-read offsets (row&7 == l16&7 for all our reads)
  const int koffA = l16 * 64 + ((lq ^ (l16 & 7)) << 3);
  const int koffB = l16 * 64 + (((4 + lq) ^ (l16 & 7)) << 3);
  const int l16h = l16 >> 3;
  const int pco  = w * 1024 + (l16 & 7);

  f32x4 oacc[4];
#pragma unroll
  for (int i = 0; i < 4; i++) oacc[i] = 0;
  float lsum[4] = {0.f, 0.f, 0.f, 0.f};

  const int nkt = qhigh + 1;
  for (int kb = 0; kb < nkt; ++kb) {
    __syncthreads();  // drains tile-kb stages; separates buf reuse
    const int cur = (kb & 1) * 4096;
    if (kb + 1 < nkt) {  // async-stage next tile into other buffer (all waves)
      const int nxt = ((kb + 1) & 1) * 4096;
      const size_t ko = (size_t)(kb + 1) * 64;
      gload_lds16(gK + ko * 3072, Ks + nxt + ldst);
      gload_lds16(gV + ko, VTs + nxt + ldst);
    }

    if (kb <= myqb) {  // wave-uniform: inactive half just meets barriers
      f32x4 sacc[4];
#pragma unroll
      for (int nt = 0; nt < 4; nt++) sacc[nt] = 0;
#pragma unroll
      for (int nt = 0; nt < 4; nt++) {
        const bf16x8 kf0 = *(const bf16x8*)(Ks + cur + nt * 1024 + koffA);
        const bf16x8 kf1 = *(const bf16x8*)(Ks + cur + nt * 1024 + koffB);
        sacc[nt] = __builtin_amdgcn_mfma_f32_16x16x32_bf16(qf0, kf0, sacc[nt], 0, 0, 0);
        sacc[nt] = __builtin_amdgcn_mfma_f32_16x16x32_bf16(qf1, kf1, sacc[nt], 0, 0, 0);
      }

      if (kb == myqb) {  // diagonal tile: masked softmax
#pragma unroll
        for (int r = 0; r < 4; r++) {
          const int rowp = lq * 4 + r;
          const int qloc = wq * 16 + rowp;
          float e[4];
#pragma unroll
          for (int nt = 0; nt < 4; nt++) {
            float sv = sacc[nt][r] * SCALE_LOG2;
            sv = fminf(sv, 88.f);
            if (nt * 16 + l16 > qloc) sv = -1e30f;
            e[nt] = exp2f(sv);
            Ps[pco + rowp * 64 + ((((nt * 2 + l16h)) ^ (rowp & 7)) << 3)] = __float2bfloat16(e[nt]);
          }
          lsum[r] += (e[0] + e[1]) + (e[2] + e[3]);
        }
      } else {  // strictly-lower tile: no mask work
#pragma unroll
        for (int r = 0; r < 4; r++) {
          const int rowp = lq * 4 + r;
          float e[4];
#pragma unroll
          for (int nt = 0; nt < 4; nt++) {
            float sv = sacc[nt][r] * SCALE_LOG2;
            sv = fminf(sv, 88.f);
            e[nt] = exp2f(sv);
            Ps[pco + rowp * 64 + ((((nt * 2 + l16h)) ^ (rowp & 7)) << 3)] = __float2bfloat16(e[nt]);
          }
          lsum[r] += (e[0] + e[1]) + (e[2] + e[3]);
        }
      }

      const bf16x8 pf0 = *(const bf16x8*)(Ps + w * 1024 + koffA);
      const bf16x8 pf1 = *(const bf16x8*)(Ps + w * 1024 + koffB);
#pragma unroll
      for (int dt = 0; dt < 4; dt++) {
        const bf16x8 vf0 = *(const bf16x8*)(VTs + cur + dt * 1024 + koffA);
        const bf16x8 vf1 = *(const bf16x8*)(VTs + cur + dt * 1024 + koffB);
        oacc[dt] = __builtin_amdgcn_mfma_f32_16x16x32_bf16(pf0, vf0, oacc[dt], 0, 0, 0);
        oacc[dt] = __builtin_amdgcn_mfma_f32_16x16x32_bf16(pf1, vf1, oacc[dt], 0, 0, 0);
      }
    }
  }

#pragma unroll
  for (int r = 0; r < 4; r++) {
    float l = lsum[r];
    l += __shfl_xor(l, 1);
    l += __shfl_xor(l, 2);
    l += __shfl_xor(l, 4);
    l += __shfl_xor(l, 8);
    lsum[r] = 1.f / l;
  }
#pragma unroll
  for (int dt = 0; dt < 4; dt++)
#pragma unroll
    for (int r = 0; r < 4; r++) {
      const int qrow_ = myqb * 64 + wq * 16 + lq * 4 + r;
      const float v = oacc[dt][r] * lsum[r];
      out[(size_t)(b * SEQ + qrow_) * DM + h * 64 + dt * 16 + l16] = __float2bfloat16(v);
    }
}

// ---------------------------------------------------------------- launch
extern "C" void kernel_launch(void* const* d_in, const int* in_sizes, int n_in,
                              void* d_out, int out_size, void* d_ws, size_t ws_size,
                              hipStream_t stream) {
  const float* x     = (const float*)d_in[0];
  const float* w_qkv = (const float*)d_in[1];
  const float* b_qkv = (const float*)d_in[2];
  const float* w_fc  = (const float*)d_in[3];
  const float* b_fc  = (const float*)d_in[4];
  const float* ln1_g = (const float*)d_in[5];
  const float* ln1_b = (const float*)d_in[6];
  const float* ln2_g = (const float*)d_in[7];
  const float* ln2_b = (const float*)d_in[8];
  const float* w1    = (const float*)d_in[9];
  const float* b1    = (const float*)d_in[10];
  const float* w2    = (const float*)d_in[11];
  const float* b2    = (const float*)d_in[12];
  float* out = (float*)d_out;

  char* ws    = (char*)d_ws;
  float* x2   = (float*)(ws);                       // 16 MB fp32 post-attn residual
  bf16* VTg   = (bf16*)(ws);                        // 8 MB V^T [b][h][d][t] — lifetime
                                                    // [qkv-gemm .. flash], disjoint from x2
  bf16* big   = (bf16*)(ws + (size_t)(16 << 20));   // 32 MB: qkv (24MB) then fc1 out (32MB)
  bf16* small = (bf16*)(ws + (size_t)(48 << 20));   // 8 MB: h1 / attn-out / h2
  bf16* wT    = (bf16*)(ws + (size_t)(56 << 20));   // 8 MB: transposed weight scratch

  const dim3 tb(32, 8);

  ln_to_bf16<<<dim3(4096), dim3(256), 0, stream>>>(x, ln1_g, ln1_b, small);
  transpose_to_bf16<<<dim3(96, 32), tb, 0, stream>>>(w_qkv, wT, 1024, 3072);
  gemm_bt<EP_QKV, 128, 128><<<dim3(32, 24), dim3(256), 0, stream>>>(
      small, wT, b_qkv, nullptr, nullptr, big, VTg, 4096, 3072, 1024);
  flash_attn<<<dim3(512), dim3(512), 0, stream>>>(big, VTg, small);
  transpose_to_bf16<<<dim3(32, 32), tb, 0, stream>>>(w_fc, wT, 1024, 1024);
  gemm_bt64<<<dim3(64, 16), dim3(256), 0, stream>>>(
      small, wT, b_fc, x, x2, 4096, 1024, 1024);
  ln_to_bf16<<<dim3(4096), dim3(256), 0, stream>>>(x2, ln2_g, ln2_b, small);
  transpose_to_bf16<<<dim3(128, 32), tb, 0, stream>>>(w1, wT, 1024, 4096);
  gemm_bt<EP_GELU, 128, 128><<<dim3(32, 32), dim3(256), 0, stream>>>(
      small, wT, b1, nullptr, nullptr, big, nullptr, 4096, 4096, 1024);
  transpose_to_bf16<<<dim3(32, 128), tb, 0, stream>>>(w2, wT, 4096, 1024);
  gemm_bt64<<<dim3(64, 16), dim3(256), 0, stream>>>(
      big, wT, b2, x2, out, 4096, 1024, 4096);
}

// Round 6
// 376.187 us; speedup vs baseline: 1.0633x; 1.0633x over previous
//
#include <hip/hip_runtime.h>
#include <hip/hip_bf16.h>
#include <cstdint>
#include <cstddef>

#define SEQ 2048
#define DM  1024

typedef __attribute__((ext_vector_type(8))) __bf16 bf16x8;
typedef __attribute__((ext_vector_type(4))) float  f32x4;
using bf16 = __hip_bfloat16;

// ---------------------------------------------------------------- helpers
__device__ __forceinline__ void gload_lds16(const bf16* g, bf16* l) {
  __builtin_amdgcn_global_load_lds((const __attribute__((address_space(1))) void*)g,
                                   (__attribute__((address_space(3))) void*)l,
                                   16, 0, 0);
}
// fused counted-wait + barrier (compiler memory fence via clobber; NO sched_barrier)
__device__ __forceinline__ void wb4() { asm volatile("s_waitcnt vmcnt(4)\n\ts_barrier" ::: "memory"); }
__device__ __forceinline__ void wb0() { asm volatile("s_waitcnt vmcnt(0)\n\ts_barrier" ::: "memory"); }

// ---------------------------------------------------------------- transpose fp32(KxN) -> bf16(NxK)
__global__ void transpose_to_bf16(const float* __restrict__ in, bf16* __restrict__ out,
                                  int K, int N) {
  __shared__ float tile[32][33];
  const int k0 = blockIdx.y * 32, n0 = blockIdx.x * 32;
  const int tx = threadIdx.x, ty = threadIdx.y;
#pragma unroll
  for (int i = ty; i < 32; i += 8)
    tile[i][tx] = in[(size_t)(k0 + i) * N + n0 + tx];
  __syncthreads();
#pragma unroll
  for (int i = ty; i < 32; i += 8)
    out[(size_t)(n0 + i) * K + k0 + tx] = __float2bfloat16(tile[tx][i]);
}

// ---------------------------------------------------------------- layernorm fp32 row -> bf16
__global__ void ln_to_bf16(const float* __restrict__ x, const float* __restrict__ g,
                           const float* __restrict__ bt, bf16* __restrict__ out) {
  const int row = blockIdx.x;
  const float4 v = ((const float4*)(x + (size_t)row * DM))[threadIdx.x];
  float s  = v.x + v.y + v.z + v.w;
  float s2 = v.x * v.x + v.y * v.y + v.z * v.z + v.w * v.w;
#pragma unroll
  for (int o = 32; o > 0; o >>= 1) { s += __shfl_down(s, o); s2 += __shfl_down(s2, o); }
  __shared__ float red[8];
  const int wave = threadIdx.x >> 6, lane = threadIdx.x & 63;
  if (lane == 0) { red[wave] = s; red[4 + wave] = s2; }
  __syncthreads();
  s  = red[0] + red[1] + red[2] + red[3];
  s2 = red[4] + red[5] + red[6] + red[7];
  const float mu  = s * (1.f / DM);
  const float var = s2 * (1.f / DM) - mu * mu;
  const float r   = rsqrtf(var + 1e-5f);
  const float4 gv = ((const float4*)g)[threadIdx.x];
  const float4 bv = ((const float4*)bt)[threadIdx.x];
  bf16* o = out + (size_t)row * DM + threadIdx.x * 4;
  o[0] = __float2bfloat16((v.x - mu) * r * gv.x + bv.x);
  o[1] = __float2bfloat16((v.y - mu) * r * gv.y + bv.y);
  o[2] = __float2bfloat16((v.z - mu) * r * gv.z + bv.z);
  o[3] = __float2bfloat16((v.w - mu) * r * gv.w + bv.w);
}

// ---------------------------------------------------------------- fat GEMM: 256x128 tile, BK=64, deep pipeline
// 8 waves / 512 thr. A: 3 buffers, prefetch distance 2. B: 2 buffers,
// distance 1, issued BEFORE A each tile so in-order vmcnt retirement makes
// entry-wait vmcnt(4) retire exactly {B(t), A(t)} while A(t+1)'s 4 loads stay
// in flight ACROSS the barrier. No drain-to-0 except the last tile.
// Cooperative-stage visibility: every wave issues the identical load sequence,
// so per-wave vmcnt + s_barrier => union visibility. LDS 128KB, 1 block/CU.
// XOR swizzle identical to gemm_bt64 (0 conflicts measured in-session).
enum { EP_BF16 = 0, EP_GELU = 1, EP_RESID = 2, EP_QKV = 3 };

template <int MODE>
__global__ __launch_bounds__(512, 2)
void gemm256(const bf16* __restrict__ A, const bf16* __restrict__ Bt,
             const float* __restrict__ bias,
             bf16* __restrict__ Cb, bf16* __restrict__ vt,
             int M, int N, int K) {
  constexpr int ATILE = 256 * 64;   // 16384 elems = 32KB
  constexpr int BTILE = 128 * 64;   // 8192 elems = 16KB
  __shared__ __attribute__((aligned(16))) bf16 As[3 * ATILE];  // 96KB
  __shared__ __attribute__((aligned(16))) bf16 Bs[2 * BTILE];  // 32KB
  const int tid = threadIdx.x;
  const int w = tid >> 6, lane = tid & 63;
  const int l16 = lane & 15, lq = lane >> 4;
  const int m0 = blockIdx.x * 256, n0 = blockIdx.y * 128;
  const int wr = (w >> 1) * 64, wc = (w & 1) * 64;

  f32x4 acc[4][4];
#pragma unroll
  for (int i = 0; i < 4; i++)
#pragma unroll
    for (int j = 0; j < 4; j++) acc[i][j] = 0;

  // staging: thread t covers row = i*64 + (tid>>3), linear LDS dest tid*16B;
  // global col-block pre-swizzled: cb_g = (tid&7) ^ (row&7)  (row&7 invariant
  // under +64). Read side XORs the same way -> conflict-free (proven).
  const int srow = tid >> 3;               // 0..63
  const int scb  = (tid & 7) ^ (srow & 7);
  const bf16* gA = A  + (size_t)(m0 + srow) * K + scb * 8;
  const bf16* gB = Bt + (size_t)(n0 + srow) * K + scb * 8;
  const int lw = w * 512;                  // wave-uniform LDS dest component

  auto stageA = [&](int t) {               // 4 loads/thread -> 32KB tile
    const int kt = t << 6;
    bf16* d = As + (t % 3) * ATILE + lw;
#pragma unroll
    for (int i = 0; i < 4; i++)
      gload_lds16(gA + (size_t)i * 64 * K + kt, d + i * 4096);
  };
  auto stageB = [&](int t) {               // 2 loads/thread -> 16KB tile
    const int kt = t << 6;
    bf16* d = Bs + (t & 1) * BTILE + lw;
#pragma unroll
    for (int j = 0; j < 2; j++)
      gload_lds16(gB + (size_t)j * 64 * K + kt, d + j * 4096);
  };

  const int NKT = K >> 6;                  // K=1024 -> 16
  stageB(0); stageA(0); stageA(1);         // loop invariant established

  const int sxa = l16 & 7;
  for (int it = 0; it < NKT; ++it) {
    if (it + 1 < NKT) wb4(); else wb0();   // {B(t),A(t)} resident; A(t+1) in flight
    if (it + 1 < NKT) stageB(it + 1);      // B first (oldest) ...
    if (it + 2 < NKT) stageA(it + 2);      // ... then A: preserves retire order
    const bf16* a  = As + (it % 3) * ATILE;
    const bf16* bb = Bs + (it & 1) * BTILE;
#pragma unroll
    for (int ks = 0; ks < 2; ks++) {
      bf16x8 af[4], bfv[4];
#pragma unroll
      for (int mi = 0; mi < 4; mi++) {
        const int row = wr + mi * 16 + l16;
        af[mi] = *(const bf16x8*)(a + row * 64 + (((ks * 4 + lq) ^ sxa) << 3));
      }
#pragma unroll
      for (int ni = 0; ni < 4; ni++) {
        const int row = wc + ni * 16 + l16;
        bfv[ni] = *(const bf16x8*)(bb + row * 64 + (((ks * 4 + lq) ^ sxa) << 3));
      }
      __builtin_amdgcn_s_setprio(1);
#pragma unroll
      for (int mi = 0; mi < 4; mi++)
#pragma unroll
        for (int ni = 0; ni < 4; ni++)
          acc[mi][ni] = __builtin_amdgcn_mfma_f32_16x16x32_bf16(af[mi], bfv[ni], acc[mi][ni], 0, 0, 0);
      __builtin_amdgcn_s_setprio(0);
    }
  }

#pragma unroll
  for (int ni = 0; ni < 4; ni++) {
    const int col = n0 + wc + ni * 16 + l16;
    const float bb = bias[col];
#pragma unroll
    for (int mi = 0; mi < 4; mi++) {
      if constexpr (MODE == EP_QKV) {
        const int row0 = m0 + wr + mi * 16 + lq * 4;
        if (col >= 2048) {
          // V part: write transposed vt[b][hd][t], 4 contiguous t per lane
          __attribute__((aligned(8))) bf16 pk[4];
#pragma unroll
          for (int r = 0; r < 4; r++) pk[r] = __float2bfloat16(acc[mi][ni][r] + bb);
          *(uint2*)(vt + (size_t)((row0 >> 11) * 1024 + (col - 2048)) * SEQ + (row0 & 2047)) =
              *(const uint2*)pk;
        } else {
#pragma unroll
          for (int r = 0; r < 4; r++)
            Cb[(size_t)(row0 + r) * N + col] = __float2bfloat16(acc[mi][ni][r] + bb);
        }
      } else {  // EP_GELU
#pragma unroll
        for (int r = 0; r < 4; r++) {
          const int row = m0 + wr + mi * 16 + lq * 4 + r;
          float v = acc[mi][ni][r] + bb;
          v = 0.5f * v * (1.0f + erff(v * 0.70710678118654752f));
          Cb[(size_t)row * N + col] = __float2bfloat16(v);
        }
      }
    }
  }
}

// ---------------------------------------------------------------- thin-N GEMM: 64x64 tile, BK=64 (round-3 proven)
// XOR-swizzled LDS (linear gload_lds dest + pre-swizzled global source + same
// XOR on ds_read_b128); 16 MFMA/wave per barrier.
__global__ __launch_bounds__(256, 4)
void gemm_bt64(const bf16* __restrict__ A, const bf16* __restrict__ Bt,
               const float* __restrict__ bias, const float* __restrict__ resid,
               float* __restrict__ Cf, int M, int N, int K) {
  constexpr int TILE = 64 * 64;  // 4096 elems = 8KB
  __shared__ __attribute__((aligned(16))) bf16 As[2 * TILE];
  __shared__ __attribute__((aligned(16))) bf16 Bs[2 * TILE];
  const int tid  = threadIdx.x;
  const int wave = tid >> 6, lane = tid & 63;
  const int l16 = lane & 15, lq = lane >> 4;
  const int m0 = blockIdx.x * 64, n0 = blockIdx.y * 64;
  const int wr = (wave >> 1) * 32, wc = (wave & 1) * 32;

  f32x4 acc[2][2];
#pragma unroll
  for (int i = 0; i < 2; i++)
#pragma unroll
    for (int j = 0; j < 2; j++) acc[i][j] = 0;

  const int srow = tid >> 3;                // 0..31 (pass0); +32 pass1
  const int scb  = (tid & 7) ^ (srow & 7);  // (srow+32)&7 == srow&7
  const bf16* ga0 = A  + (size_t)(m0 + srow) * K + scb * 8;
  const bf16* ga1 = A  + (size_t)(m0 + srow + 32) * K + scb * 8;
  const bf16* gb0 = Bt + (size_t)(n0 + srow) * K + scb * 8;
  const bf16* gb1 = Bt + (size_t)(n0 + srow + 32) * K + scb * 8;
  const int ld0 = wave * 512;        // wave-uniform LDS dest (elems)
  const int ld1 = 2048 + wave * 512;

  gload_lds16(ga0, As + ld0);
  gload_lds16(ga1, As + ld1);
  gload_lds16(gb0, Bs + ld0);
  gload_lds16(gb1, Bs + ld1);

  const int sxa = l16 & 7;

  const int NKT = K >> 6;
  for (int it = 0; it < NKT; ++it) {
    __syncthreads();
    const int cur = (it & 1) * TILE;
    if (it + 1 < NKT) {
      const int nxt = ((it + 1) & 1) * TILE;
      const int kt = (it + 1) << 6;
      gload_lds16(ga0 + kt, As + nxt + ld0);
      gload_lds16(ga1 + kt, As + nxt + ld1);
      gload_lds16(gb0 + kt, Bs + nxt + ld0);
      gload_lds16(gb1 + kt, Bs + nxt + ld1);
    }
    bf16x8 af[2][2], bfv[2][2];
#pragma unroll
    for (int mi = 0; mi < 2; mi++) {
      const int row = wr + mi * 16 + l16;
#pragma unroll
      for (int kk = 0; kk < 2; kk++)
        af[mi][kk] = *(const bf16x8*)(As + cur + row * 64 + (((kk * 4 + lq) ^ sxa) << 3));
    }
#pragma unroll
    for (int ni = 0; ni < 2; ni++) {
      const int row = wc + ni * 16 + l16;
#pragma unroll
      for (int kk = 0; kk < 2; kk++)
        bfv[ni][kk] = *(const bf16x8*)(Bs + cur + row * 64 + (((kk * 4 + lq) ^ sxa) << 3));
    }
#pragma unroll
    for (int kk = 0; kk < 2; kk++)
#pragma unroll
      for (int mi = 0; mi < 2; mi++)
#pragma unroll
        for (int ni = 0; ni < 2; ni++)
          acc[mi][ni] = __builtin_amdgcn_mfma_f32_16x16x32_bf16(af[mi][kk], bfv[ni][kk],
                                                                acc[mi][ni], 0, 0, 0);
  }

#pragma unroll
  for (int ni = 0; ni < 2; ni++) {
    const int col = n0 + wc + ni * 16 + l16;
    const float bb = bias[col];
#pragma unroll
    for (int mi = 0; mi < 2; mi++) {
#pragma unroll
      for (int r = 0; r < 4; r++) {
        const int row = m0 + wr + mi * 16 + lq * 4 + r;
        const size_t idx = (size_t)row * N + col;
        Cf[idx] = resid[idx] + acc[mi][ni][r] + bb;
      }
    }
  }
}

// ---------------------------------------------------------------- flash attention v5 (causal, pair-shared; round-3 proven)
#define SCALE_LOG2 0.18033688011112042f  /* 0.125 * log2(e) */

__global__ __launch_bounds__(512, 2)
void flash_attn(const bf16* __restrict__ qkv, const bf16* __restrict__ VTg,
                bf16* __restrict__ out) {
  const int idx  = blockIdx.x;
  const int praw = idx & 15;
  const int p    = ((idx >> 8) & 1) ? (15 - praw) : praw;
  const int bh   = (idx >> 4) & 31;
  const int h    = bh & 15;
  const int b    = bh >> 4;
  const int qlow = p, qhigh = 31 - p;

  const int tid = threadIdx.x;
  const int w = tid >> 6, lane = tid & 63;
  const int wq = w & 3, hf = w >> 2;  // hf=0 -> qhigh, hf=1 -> qlow
  const int l16 = lane & 15, lq = lane >> 4;
  const int myqb = hf ? qlow : qhigh;

  const size_t base = (size_t)b * SEQ * 3072;
  const bf16* Qg = qkv + base + (size_t)h * 64;
  const bf16* Kg = qkv + base + 1024 + (size_t)h * 64;
  const bf16* Vt = VTg + (size_t)(b * 1024 + h * 64) * SEQ;  // [d][t] rows

  __shared__ __attribute__((aligned(16))) bf16 Ks[2 * 4096];
  __shared__ __attribute__((aligned(16))) bf16 VTs[2 * 4096];
  __shared__ __attribute__((aligned(16))) bf16 Ps[8 * 1024];

  const int srow = tid >> 3;                 // 0..63
  const int scb  = (tid & 7) ^ (srow & 7);
  const bf16* gK = Kg + (size_t)srow * 3072 + scb * 8;
  const bf16* gV = Vt + (size_t)srow * SEQ + scb * 8;
  const int ldst = w * 512;                  // wave-uniform LDS dest (elems)

  gload_lds16(gK, Ks + ldst);
  gload_lds16(gV, VTs + ldst);

  const bf16* qrow = Qg + (size_t)(myqb * 64 + wq * 16 + l16) * 3072 + lq * 8;
  const bf16x8 qf0 = *(const bf16x8*)(qrow);
  const bf16x8 qf1 = *(const bf16x8*)(qrow + 32);

  const int koffA = l16 * 64 + ((lq ^ (l16 & 7)) << 3);
  const int koffB = l16 * 64 + (((4 + lq) ^ (l16 & 7)) << 3);
  const int l16h = l16 >> 3;
  const int pco  = w * 1024 + (l16 & 7);

  f32x4 oacc[4];
#pragma unroll
  for (int i = 0; i < 4; i++) oacc[i] = 0;
  float lsum[4] = {0.f, 0.f, 0.f, 0.f};

  const int nkt = qhigh + 1;
  for (int kb = 0; kb < nkt; ++kb) {
    __syncthreads();  // drains tile-kb stages; separates buf reuse
    const int cur = (kb & 1) * 4096;
    if (kb + 1 < nkt) {
      const int nxt = ((kb + 1) & 1) * 4096;
      const size_t ko = (size_t)(kb + 1) * 64;
      gload_lds16(gK + ko * 3072, Ks + nxt + ldst);
      gload_lds16(gV + ko, VTs + nxt + ldst);
    }

    if (kb <= myqb) {  // wave-uniform: inactive half just meets barriers
      f32x4 sacc[4];
#pragma unroll
      for (int nt = 0; nt < 4; nt++) sacc[nt] = 0;
#pragma unroll
      for (int nt = 0; nt < 4; nt++) {
        const bf16x8 kf0 = *(const bf16x8*)(Ks + cur + nt * 1024 + koffA);
        const bf16x8 kf1 = *(const bf16x8*)(Ks + cur + nt * 1024 + koffB);
        sacc[nt] = __builtin_amdgcn_mfma_f32_16x16x32_bf16(qf0, kf0, sacc[nt], 0, 0, 0);
        sacc[nt] = __builtin_amdgcn_mfma_f32_16x16x32_bf16(qf1, kf1, sacc[nt], 0, 0, 0);
      }

      if (kb == myqb) {  // diagonal tile: masked softmax
#pragma unroll
        for (int r = 0; r < 4; r++) {
          const int rowp = lq * 4 + r;
          const int qloc = wq * 16 + rowp;
          float e[4];
#pragma unroll
          for (int nt = 0; nt < 4; nt++) {
            float sv = sacc[nt][r] * SCALE_LOG2;
            sv = fminf(sv, 88.f);
            if (nt * 16 + l16 > qloc) sv = -1e30f;
            e[nt] = exp2f(sv);
            Ps[pco + rowp * 64 + ((((nt * 2 + l16h)) ^ (rowp & 7)) << 3)] = __float2bfloat16(e[nt]);
          }
          lsum[r] += (e[0] + e[1]) + (e[2] + e[3]);
        }
      } else {
#pragma unroll
        for (int r = 0; r < 4; r++) {
          const int rowp = lq * 4 + r;
          float e[4];
#pragma unroll
          for (int nt = 0; nt < 4; nt++) {
            float sv = sacc[nt][r] * SCALE_LOG2;
            sv = fminf(sv, 88.f);
            e[nt] = exp2f(sv);
            Ps[pco + rowp * 64 + ((((nt * 2 + l16h)) ^ (rowp & 7)) << 3)] = __float2bfloat16(e[nt]);
          }
          lsum[r] += (e[0] + e[1]) + (e[2] + e[3]);
        }
      }

      const bf16x8 pf0 = *(const bf16x8*)(Ps + w * 1024 + koffA);
      const bf16x8 pf1 = *(const bf16x8*)(Ps + w * 1024 + koffB);
#pragma unroll
      for (int dt = 0; dt < 4; dt++) {
        const bf16x8 vf0 = *(const bf16x8*)(VTs + cur + dt * 1024 + koffA);
        const bf16x8 vf1 = *(const bf16x8*)(VTs + cur + dt * 1024 + koffB);
        oacc[dt] = __builtin_amdgcn_mfma_f32_16x16x32_bf16(pf0, vf0, oacc[dt], 0, 0, 0);
        oacc[dt] = __builtin_amdgcn_mfma_f32_16x16x32_bf16(pf1, vf1, oacc[dt], 0, 0, 0);
      }
    }
  }

#pragma unroll
  for (int r = 0; r < 4; r++) {
    float l = lsum[r];
    l += __shfl_xor(l, 1);
    l += __shfl_xor(l, 2);
    l += __shfl_xor(l, 4);
    l += __shfl_xor(l, 8);
    lsum[r] = 1.f / l;
  }
#pragma unroll
  for (int dt = 0; dt < 4; dt++)
#pragma unroll
    for (int r = 0; r < 4; r++) {
      const int qrow_ = myqb * 64 + wq * 16 + lq * 4 + r;
      const float v = oacc[dt][r] * lsum[r];
      out[(size_t)(b * SEQ + qrow_) * DM + h * 64 + dt * 16 + l16] = __float2bfloat16(v);
    }
}

// ---------------------------------------------------------------- launch
extern "C" void kernel_launch(void* const* d_in, const int* in_sizes, int n_in,
                              void* d_out, int out_size, void* d_ws, size_t ws_size,
                              hipStream_t stream) {
  const float* x     = (const float*)d_in[0];
  const float* w_qkv = (const float*)d_in[1];
  const float* b_qkv = (const float*)d_in[2];
  const float* w_fc  = (const float*)d_in[3];
  const float* b_fc  = (const float*)d_in[4];
  const float* ln1_g = (const float*)d_in[5];
  const float* ln1_b = (const float*)d_in[6];
  const float* ln2_g = (const float*)d_in[7];
  const float* ln2_b = (const float*)d_in[8];
  const float* w1    = (const float*)d_in[9];
  const float* b1    = (const float*)d_in[10];
  const float* w2    = (const float*)d_in[11];
  const float* b2    = (const float*)d_in[12];
  float* out = (float*)d_out;

  char* ws    = (char*)d_ws;
  float* x2   = (float*)(ws);                       // 16 MB fp32 post-attn residual
  bf16* VTg   = (bf16*)(ws);                        // 8 MB V^T [b][h][d][t] — lifetime
                                                    // [qkv-gemm .. flash], disjoint from x2
  bf16* big   = (bf16*)(ws + (size_t)(16 << 20));   // 32 MB: qkv (24MB) then fc1 out (32MB)
  bf16* small = (bf16*)(ws + (size_t)(48 << 20));   // 8 MB: h1 / attn-out / h2
  bf16* wT    = (bf16*)(ws + (size_t)(56 << 20));   // 8 MB: transposed weight scratch

  const dim3 tb(32, 8);

  ln_to_bf16<<<dim3(4096), dim3(256), 0, stream>>>(x, ln1_g, ln1_b, small);
  transpose_to_bf16<<<dim3(96, 32), tb, 0, stream>>>(w_qkv, wT, 1024, 3072);
  gemm256<EP_QKV><<<dim3(16, 24), dim3(512), 0, stream>>>(
      small, wT, b_qkv, big, VTg, 4096, 3072, 1024);
  flash_attn<<<dim3(512), dim3(512), 0, stream>>>(big, VTg, small);
  transpose_to_bf16<<<dim3(32, 32), tb, 0, stream>>>(w_fc, wT, 1024, 1024);
  gemm_bt64<<<dim3(64, 16), dim3(256), 0, stream>>>(
      small, wT, b_fc, x, x2, 4096, 1024, 1024);
  ln_to_bf16<<<dim3(4096), dim3(256), 0, stream>>>(x2, ln2_g, ln2_b, small);
  transpose_to_bf16<<<dim3(128, 32), tb, 0, stream>>>(w1, wT, 1024, 4096);
  gemm256<EP_GELU><<<dim3(16, 32), dim3(512), 0, stream>>>(
      small, wT, b1, big, nullptr, 4096, 4096, 1024);
  transpose_to_bf16<<<dim3(32, 128), tb, 0, stream>>>(w2, wT, 4096, 1024);
  gemm_bt64<<<dim3(64, 16), dim3(256), 0, stream>>>(
      big, wT, b2, x2, out, 4096, 1024, 4096);
}

// Round 7
// 345.022 us; speedup vs baseline: 1.1593x; 1.0903x over previous
//
#include <hip/hip_runtime.h>
#include <hip/hip_bf16.h>
#include <cstdint>
#include <cstddef>

#define SEQ 2048
#define DM  1024

typedef __attribute__((ext_vector_type(8))) __bf16 bf16x8;
typedef __attribute__((ext_vector_type(4))) float  f32x4;
using bf16 = __hip_bfloat16;

// ---------------------------------------------------------------- helpers
__device__ __forceinline__ void gload_lds16(const bf16* g, bf16* l) {
  __builtin_amdgcn_global_load_lds((const __attribute__((address_space(1))) void*)g,
                                   (__attribute__((address_space(3))) void*)l,
                                   16, 0, 0);
}

// XCD-chunked 4x4-supertile block remap (bijective: NWG%8==0, GM%4==0, GN%4==0).
// id&7 -> XCD (HW round-robins dispatch id over 8 XCDs); each XCD gets a
// CONTIGUOUS chunk of the tile grid, walked in 4x4 supertiles (m-fastest):
// instantaneous working set ~2-4MB -> fits the 4MB per-XCD L2, so 2-phase
// staging loads hit L2 (~200cy) instead of L3/HBM (~600-900cy).
template <int GM, int GN>
__device__ __forceinline__ void remap_wg(int id, int& bm, int& bn) {
  constexpr int NWG = GM * GN;
  constexpr int CPX = NWG / 8;
  id = (id & 7) * CPX + (id >> 3);
  const int st = id >> 4, wi = id & 15;
  constexpr int STM = GM / 4;
  bm = (st % STM) * 4 + (wi & 3);
  bn = (st / STM) * 4 + (wi >> 2);
}

// ---------------------------------------------------------------- transpose fp32(KxN) -> bf16(NxK)
__global__ void transpose_to_bf16(const float* __restrict__ in, bf16* __restrict__ out,
                                  int K, int N) {
  __shared__ float tile[32][33];
  const int k0 = blockIdx.y * 32, n0 = blockIdx.x * 32;
  const int tx = threadIdx.x, ty = threadIdx.y;
#pragma unroll
  for (int i = ty; i < 32; i += 8)
    tile[i][tx] = in[(size_t)(k0 + i) * N + n0 + tx];
  __syncthreads();
#pragma unroll
  for (int i = ty; i < 32; i += 8)
    out[(size_t)(n0 + i) * K + k0 + tx] = __float2bfloat16(tile[tx][i]);
}

// ---------------------------------------------------------------- layernorm fp32 row -> bf16
__global__ void ln_to_bf16(const float* __restrict__ x, const float* __restrict__ g,
                           const float* __restrict__ bt, bf16* __restrict__ out) {
  const int row = blockIdx.x;
  const float4 v = ((const float4*)(x + (size_t)row * DM))[threadIdx.x];
  float s  = v.x + v.y + v.z + v.w;
  float s2 = v.x * v.x + v.y * v.y + v.z * v.z + v.w * v.w;
#pragma unroll
  for (int o = 32; o > 0; o >>= 1) { s += __shfl_down(s, o); s2 += __shfl_down(s2, o); }
  __shared__ float red[8];
  const int wave = threadIdx.x >> 6, lane = threadIdx.x & 63;
  if (lane == 0) { red[wave] = s; red[4 + wave] = s2; }
  __syncthreads();
  s  = red[0] + red[1] + red[2] + red[3];
  s2 = red[4] + red[5] + red[6] + red[7];
  const float mu  = s * (1.f / DM);
  const float var = s2 * (1.f / DM) - mu * mu;
  const float r   = rsqrtf(var + 1e-5f);
  const float4 gv = ((const float4*)g)[threadIdx.x];
  const float4 bv = ((const float4*)bt)[threadIdx.x];
  bf16* o = out + (size_t)row * DM + threadIdx.x * 4;
  o[0] = __float2bfloat16((v.x - mu) * r * gv.x + bv.x);
  o[1] = __float2bfloat16((v.y - mu) * r * gv.y + bv.y);
  o[2] = __float2bfloat16((v.z - mu) * r * gv.z + bv.z);
  o[3] = __float2bfloat16((v.w - mu) * r * gv.w + bv.w);
}

// ---------------------------------------------------------------- GEMM: C = A(MxK) @ Bt(NxK)^T + bias
// 128x128 tiles, BK=32, double-buffered single-barrier K-loop (round-3 proven
// structure) + supertile/XCD block remap (1D grid).
enum { EP_BF16 = 0, EP_GELU = 1, EP_RESID = 2, EP_QKV = 3 };

template <int MODE, int TM, int TN, int GM, int GN>
__global__ void gemm_bt(const bf16* __restrict__ A, const bf16* __restrict__ Bt,
                        const float* __restrict__ bias, const float* __restrict__ resid,
                        float* __restrict__ Cf, bf16* __restrict__ Cb, bf16* __restrict__ vt,
                        int M, int N, int K) {
  constexpr int ABUF = TM * 32;
  constexpr int BBUF = TN * 32;
  constexpr int MI = TM / 32;
  constexpr int NI = TN / 32;
  __shared__ __attribute__((aligned(16))) bf16 As[2 * ABUF];
  __shared__ __attribute__((aligned(16))) bf16 Bs[2 * BBUF];
  const int tid  = threadIdx.x;
  const int wave = tid >> 6, lane = tid & 63;
  const int l16 = lane & 15, lq = lane >> 4;
  int bm, bn;
  remap_wg<GM, GN>(blockIdx.x, bm, bn);
  const int m0 = bm * TM, n0 = bn * TN;
  const int wr = (wave >> 1) * (TM / 2), wc = (wave & 1) * (TN / 2);

  f32x4 acc[MI][NI];
#pragma unroll
  for (int i = 0; i < MI; i++)
#pragma unroll
    for (int j = 0; j < NI; j++) acc[i][j] = 0;

  const int srow = tid >> 2;
  const int scol = (tid & 3) * 8;
  const bf16* ga = A  + (size_t)(m0 + srow) * K + scol;
  const bf16* gb = Bt + (size_t)(n0 + srow) * K + scol;

  // stage tile 0 -> buffer 0
  {
    bf16* la = As + wave * 512;
    bf16* lb = Bs + wave * 512;
    gload_lds16(ga, la);
    if (TM == 128) gload_lds16(ga + (size_t)64 * K, la + 2048);
    gload_lds16(gb, lb);
    if (TN == 128) gload_lds16(gb + (size_t)64 * K, lb + 2048);
  }

  const int NKT = K >> 5;
  for (int it = 0; it < NKT; ++it) {
    __syncthreads();  // drains tile-it loads (only ones outstanding); aligns waves
    const int cur = it & 1, nxt = cur ^ 1;
    if (it + 1 < NKT) {  // async-stage tile it+1; overlaps MFMA below
      const int kt = (it + 1) << 5;
      bf16* la = As + nxt * ABUF + wave * 512;
      bf16* lb = Bs + nxt * BBUF + wave * 512;
      gload_lds16(ga + kt, la);
      if (TM == 128) gload_lds16(ga + (size_t)64 * K + kt, la + 2048);
      gload_lds16(gb + kt, lb);
      if (TN == 128) gload_lds16(gb + (size_t)64 * K + kt, lb + 2048);
    }
    bf16x8 af[MI], bfr[NI];
#pragma unroll
    for (int mi = 0; mi < MI; mi++)
      af[mi] = *(const bf16x8*)(As + cur * ABUF + (wr + mi * 16 + l16) * 32 + lq * 8);
#pragma unroll
    for (int ni = 0; ni < NI; ni++)
      bfr[ni] = *(const bf16x8*)(Bs + cur * BBUF + (wc + ni * 16 + l16) * 32 + lq * 8);
#pragma unroll
    for (int mi = 0; mi < MI; mi++)
#pragma unroll
      for (int ni = 0; ni < NI; ni++)
        acc[mi][ni] = __builtin_amdgcn_mfma_f32_16x16x32_bf16(af[mi], bfr[ni], acc[mi][ni], 0, 0, 0);
  }

#pragma unroll
  for (int ni = 0; ni < NI; ni++) {
    const int col = n0 + wc + ni * 16 + l16;
    const float bb = bias[col];
#pragma unroll
    for (int mi = 0; mi < MI; mi++) {
      if constexpr (MODE == EP_QKV) {
        const int row0 = m0 + wr + mi * 16 + lq * 4;
        if (col >= 2048) {
          // V part: write transposed vt[b][hd][t], 4 contiguous t per lane
          __attribute__((aligned(8))) bf16 pk[4];
#pragma unroll
          for (int r = 0; r < 4; r++) pk[r] = __float2bfloat16(acc[mi][ni][r] + bb);
          *(uint2*)(vt + (size_t)((row0 >> 11) * 1024 + (col - 2048)) * SEQ + (row0 & 2047)) =
              *(const uint2*)pk;
        } else {
#pragma unroll
          for (int r = 0; r < 4; r++)
            Cb[(size_t)(row0 + r) * N + col] = __float2bfloat16(acc[mi][ni][r] + bb);
        }
      } else {
#pragma unroll
        for (int r = 0; r < 4; r++) {
          const int row = m0 + wr + mi * 16 + lq * 4 + r;
          const size_t idx = (size_t)row * N + col;
          float v = acc[mi][ni][r] + bb;
          if (MODE == EP_BF16) {
            Cb[idx] = __float2bfloat16(v);
          } else if (MODE == EP_GELU) {
            v = 0.5f * v * (1.0f + erff(v * 0.70710678118654752f));
            Cb[idx] = __float2bfloat16(v);
          } else {
            Cf[idx] = resid[idx] + v;
          }
        }
      }
    }
  }
}

// ---------------------------------------------------------------- thin-N GEMM: 64x64 tile, BK=64 (round-3 proven)
// XOR-swizzled LDS (linear gload_lds dest + pre-swizzled global source + same
// XOR on ds_read_b128); 16 MFMA/wave per barrier. + supertile/XCD remap.
template <int GM, int GN>
__global__ __launch_bounds__(256, 4)
void gemm_bt64(const bf16* __restrict__ A, const bf16* __restrict__ Bt,
               const float* __restrict__ bias, const float* __restrict__ resid,
               float* __restrict__ Cf, int M, int N, int K) {
  constexpr int TILE = 64 * 64;  // 4096 elems = 8KB
  __shared__ __attribute__((aligned(16))) bf16 As[2 * TILE];
  __shared__ __attribute__((aligned(16))) bf16 Bs[2 * TILE];
  const int tid  = threadIdx.x;
  const int wave = tid >> 6, lane = tid & 63;
  const int l16 = lane & 15, lq = lane >> 4;
  int bm, bn;
  remap_wg<GM, GN>(blockIdx.x, bm, bn);
  const int m0 = bm * 64, n0 = bn * 64;
  const int wr = (wave >> 1) * 32, wc = (wave & 1) * 32;

  f32x4 acc[2][2];
#pragma unroll
  for (int i = 0; i < 2; i++)
#pragma unroll
    for (int j = 0; j < 2; j++) acc[i][j] = 0;

  const int srow = tid >> 3;                // 0..31 (pass0); +32 pass1
  const int scb  = (tid & 7) ^ (srow & 7);  // (srow+32)&7 == srow&7
  const bf16* ga0 = A  + (size_t)(m0 + srow) * K + scb * 8;
  const bf16* ga1 = A  + (size_t)(m0 + srow + 32) * K + scb * 8;
  const bf16* gb0 = Bt + (size_t)(n0 + srow) * K + scb * 8;
  const bf16* gb1 = Bt + (size_t)(n0 + srow + 32) * K + scb * 8;
  const int ld0 = wave * 512;        // wave-uniform LDS dest (elems)
  const int ld1 = 2048 + wave * 512;

  gload_lds16(ga0, As + ld0);
  gload_lds16(ga1, As + ld1);
  gload_lds16(gb0, Bs + ld0);
  gload_lds16(gb1, Bs + ld1);

  const int sxa = l16 & 7;

  const int NKT = K >> 6;
  for (int it = 0; it < NKT; ++it) {
    __syncthreads();
    const int cur = (it & 1) * TILE;
    if (it + 1 < NKT) {
      const int nxt = ((it + 1) & 1) * TILE;
      const int kt = (it + 1) << 6;
      gload_lds16(ga0 + kt, As + nxt + ld0);
      gload_lds16(ga1 + kt, As + nxt + ld1);
      gload_lds16(gb0 + kt, Bs + nxt + ld0);
      gload_lds16(gb1 + kt, Bs + nxt + ld1);
    }
    bf16x8 af[2][2], bfv[2][2];
#pragma unroll
    for (int mi = 0; mi < 2; mi++) {
      const int row = wr + mi * 16 + l16;
#pragma unroll
      for (int kk = 0; kk < 2; kk++)
        af[mi][kk] = *(const bf16x8*)(As + cur + row * 64 + (((kk * 4 + lq) ^ sxa) << 3));
    }
#pragma unroll
    for (int ni = 0; ni < 2; ni++) {
      const int row = wc + ni * 16 + l16;
#pragma unroll
      for (int kk = 0; kk < 2; kk++)
        bfv[ni][kk] = *(const bf16x8*)(Bs + cur + row * 64 + (((kk * 4 + lq) ^ sxa) << 3));
    }
#pragma unroll
    for (int kk = 0; kk < 2; kk++)
#pragma unroll
      for (int mi = 0; mi < 2; mi++)
#pragma unroll
        for (int ni = 0; ni < 2; ni++)
          acc[mi][ni] = __builtin_amdgcn_mfma_f32_16x16x32_bf16(af[mi][kk], bfv[ni][kk],
                                                                acc[mi][ni], 0, 0, 0);
  }

#pragma unroll
  for (int ni = 0; ni < 2; ni++) {
    const int col = n0 + wc + ni * 16 + l16;
    const float bb = bias[col];
#pragma unroll
    for (int mi = 0; mi < 2; mi++) {
#pragma unroll
      for (int r = 0; r < 4; r++) {
        const int row = m0 + wr + mi * 16 + lq * 4 + r;
        const size_t idx = (size_t)row * N + col;
        Cf[idx] = resid[idx] + acc[mi][ni][r] + bb;
      }
    }
  }
}

// ---------------------------------------------------------------- flash attention v5 (causal, pair-shared; round-3 proven)
#define SCALE_LOG2 0.18033688011112042f  /* 0.125 * log2(e) */

__global__ __launch_bounds__(512, 2)
void flash_attn(const bf16* __restrict__ qkv, const bf16* __restrict__ VTg,
                bf16* __restrict__ out) {
  const int idx  = blockIdx.x;
  const int praw = idx & 15;
  const int p    = ((idx >> 8) & 1) ? (15 - praw) : praw;
  const int bh   = (idx >> 4) & 31;
  const int h    = bh & 15;
  const int b    = bh >> 4;
  const int qlow = p, qhigh = 31 - p;

  const int tid = threadIdx.x;
  const int w = tid >> 6, lane = tid & 63;
  const int wq = w & 3, hf = w >> 2;  // hf=0 -> qhigh, hf=1 -> qlow
  const int l16 = lane & 15, lq = lane >> 4;
  const int myqb = hf ? qlow : qhigh;

  const size_t base = (size_t)b * SEQ * 3072;
  const bf16* Qg = qkv + base + (size_t)h * 64;
  const bf16* Kg = qkv + base + 1024 + (size_t)h * 64;
  const bf16* Vt = VTg + (size_t)(b * 1024 + h * 64) * SEQ;  // [d][t] rows

  __shared__ __attribute__((aligned(16))) bf16 Ks[2 * 4096];
  __shared__ __attribute__((aligned(16))) bf16 VTs[2 * 4096];
  __shared__ __attribute__((aligned(16))) bf16 Ps[8 * 1024];

  const int srow = tid >> 3;                 // 0..63
  const int scb  = (tid & 7) ^ (srow & 7);
  const bf16* gK = Kg + (size_t)srow * 3072 + scb * 8;
  const bf16* gV = Vt + (size_t)srow * SEQ + scb * 8;
  const int ldst = w * 512;                  // wave-uniform LDS dest (elems)

  gload_lds16(gK, Ks + ldst);
  gload_lds16(gV, VTs + ldst);

  const bf16* qrow = Qg + (size_t)(myqb * 64 + wq * 16 + l16) * 3072 + lq * 8;
  const bf16x8 qf0 = *(const bf16x8*)(qrow);
  const bf16x8 qf1 = *(const bf16x8*)(qrow + 32);

  const int koffA = l16 * 64 + ((lq ^ (l16 & 7)) << 3);
  const int koffB = l16 * 64 + (((4 + lq) ^ (l16 & 7)) << 3);
  const int l16h = l16 >> 3;
  const int pco  = w * 1024 + (l16 & 7);

  f32x4 oacc[4];
#pragma unroll
  for (int i = 0; i < 4; i++) oacc[i] = 0;
  float lsum[4] = {0.f, 0.f, 0.f, 0.f};

  const int nkt = qhigh + 1;
  for (int kb = 0; kb < nkt; ++kb) {
    __syncthreads();  // drains tile-kb stages; separates buf reuse
    const int cur = (kb & 1) * 4096;
    if (kb + 1 < nkt) {
      const int nxt = ((kb + 1) & 1) * 4096;
      const size_t ko = (size_t)(kb + 1) * 64;
      gload_lds16(gK + ko * 3072, Ks + nxt + ldst);
      gload_lds16(gV + ko, VTs + nxt + ldst);
    }

    if (kb <= myqb) {  // wave-uniform: inactive half just meets barriers
      f32x4 sacc[4];
#pragma unroll
      for (int nt = 0; nt < 4; nt++) sacc[nt] = 0;
#pragma unroll
      for (int nt = 0; nt < 4; nt++) {
        const bf16x8 kf0 = *(const bf16x8*)(Ks + cur + nt * 1024 + koffA);
        const bf16x8 kf1 = *(const bf16x8*)(Ks + cur + nt * 1024 + koffB);
        sacc[nt] = __builtin_amdgcn_mfma_f32_16x16x32_bf16(qf0, kf0, sacc[nt], 0, 0, 0);
        sacc[nt] = __builtin_amdgcn_mfma_f32_16x16x32_bf16(qf1, kf1, sacc[nt], 0, 0, 0);
      }

      if (kb == myqb) {  // diagonal tile: masked softmax
#pragma unroll
        for (int r = 0; r < 4; r++) {
          const int rowp = lq * 4 + r;
          const int qloc = wq * 16 + rowp;
          float e[4];
#pragma unroll
          for (int nt = 0; nt < 4; nt++) {
            float sv = sacc[nt][r] * SCALE_LOG2;
            sv = fminf(sv, 88.f);
            if (nt * 16 + l16 > qloc) sv = -1e30f;
            e[nt] = exp2f(sv);
            Ps[pco + rowp * 64 + ((((nt * 2 + l16h)) ^ (rowp & 7)) << 3)] = __float2bfloat16(e[nt]);
          }
          lsum[r] += (e[0] + e[1]) + (e[2] + e[3]);
        }
      } else {
#pragma unroll
        for (int r = 0; r < 4; r++) {
          const int rowp = lq * 4 + r;
          float e[4];
#pragma unroll
          for (int nt = 0; nt < 4; nt++) {
            float sv = sacc[nt][r] * SCALE_LOG2;
            sv = fminf(sv, 88.f);
            e[nt] = exp2f(sv);
            Ps[pco + rowp * 64 + ((((nt * 2 + l16h)) ^ (rowp & 7)) << 3)] = __float2bfloat16(e[nt]);
          }
          lsum[r] += (e[0] + e[1]) + (e[2] + e[3]);
        }
      }

      const bf16x8 pf0 = *(const bf16x8*)(Ps + w * 1024 + koffA);
      const bf16x8 pf1 = *(const bf16x8*)(Ps + w * 1024 + koffB);
#pragma unroll
      for (int dt = 0; dt < 4; dt++) {
        const bf16x8 vf0 = *(const bf16x8*)(VTs + cur + dt * 1024 + koffA);
        const bf16x8 vf1 = *(const bf16x8*)(VTs + cur + dt * 1024 + koffB);
        oacc[dt] = __builtin_amdgcn_mfma_f32_16x16x32_bf16(pf0, vf0, oacc[dt], 0, 0, 0);
        oacc[dt] = __builtin_amdgcn_mfma_f32_16x16x32_bf16(pf1, vf1, oacc[dt], 0, 0, 0);
      }
    }
  }

#pragma unroll
  for (int r = 0; r < 4; r++) {
    float l = lsum[r];
    l += __shfl_xor(l, 1);
    l += __shfl_xor(l, 2);
    l += __shfl_xor(l, 4);
    l += __shfl_xor(l, 8);
    lsum[r] = 1.f / l;
  }
#pragma unroll
  for (int dt = 0; dt < 4; dt++)
#pragma unroll
    for (int r = 0; r < 4; r++) {
      const int qrow_ = myqb * 64 + wq * 16 + lq * 4 + r;
      const float v = oacc[dt][r] * lsum[r];
      out[(size_t)(b * SEQ + qrow_) * DM + h * 64 + dt * 16 + l16] = __float2bfloat16(v);
    }
}

// ---------------------------------------------------------------- launch
extern "C" void kernel_launch(void* const* d_in, const int* in_sizes, int n_in,
                              void* d_out, int out_size, void* d_ws, size_t ws_size,
                              hipStream_t stream) {
  const float* x     = (const float*)d_in[0];
  const float* w_qkv = (const float*)d_in[1];
  const float* b_qkv = (const float*)d_in[2];
  const float* w_fc  = (const float*)d_in[3];
  const float* b_fc  = (const float*)d_in[4];
  const float* ln1_g = (const float*)d_in[5];
  const float* ln1_b = (const float*)d_in[6];
  const float* ln2_g = (const float*)d_in[7];
  const float* ln2_b = (const float*)d_in[8];
  const float* w1    = (const float*)d_in[9];
  const float* b1    = (const float*)d_in[10];
  const float* w2    = (const float*)d_in[11];
  const float* b2    = (const float*)d_in[12];
  float* out = (float*)d_out;

  char* ws    = (char*)d_ws;
  float* x2   = (float*)(ws);                       // 16 MB fp32 post-attn residual
  bf16* VTg   = (bf16*)(ws);                        // 8 MB V^T [b][h][d][t] — lifetime
                                                    // [qkv-gemm .. flash], disjoint from x2
  bf16* big   = (bf16*)(ws + (size_t)(16 << 20));   // 32 MB: qkv (24MB) then fc1 out (32MB)
  bf16* small = (bf16*)(ws + (size_t)(48 << 20));   // 8 MB: h1 / attn-out / h2
  bf16* wT    = (bf16*)(ws + (size_t)(56 << 20));   // 8 MB: transposed weight scratch

  const dim3 tb(32, 8);

  ln_to_bf16<<<dim3(4096), dim3(256), 0, stream>>>(x, ln1_g, ln1_b, small);
  transpose_to_bf16<<<dim3(96, 32), tb, 0, stream>>>(w_qkv, wT, 1024, 3072);
  gemm_bt<EP_QKV, 128, 128, 32, 24><<<dim3(768), dim3(256), 0, stream>>>(
      small, wT, b_qkv, nullptr, nullptr, big, VTg, 4096, 3072, 1024);
  flash_attn<<<dim3(512), dim3(512), 0, stream>>>(big, VTg, small);
  transpose_to_bf16<<<dim3(32, 32), tb, 0, stream>>>(w_fc, wT, 1024, 1024);
  gemm_bt64<64, 16><<<dim3(1024), dim3(256), 0, stream>>>(
      small, wT, b_fc, x, x2, 4096, 1024, 1024);
  ln_to_bf16<<<dim3(4096), dim3(256), 0, stream>>>(x2, ln2_g, ln2_b, small);
  transpose_to_bf16<<<dim3(128, 32), tb, 0, stream>>>(w1, wT, 1024, 4096);
  gemm_bt<EP_GELU, 128, 128, 32, 32><<<dim3(1024), dim3(256), 0, stream>>>(
      small, wT, b1, nullptr, nullptr, big, nullptr, 4096, 4096, 1024);
  transpose_to_bf16<<<dim3(32, 128), tb, 0, stream>>>(w2, wT, 4096, 1024);
  gemm_bt64<64, 16><<<dim3(1024), dim3(256), 0, stream>>>(
      big, wT, b2, x2, out, 4096, 1024, 4096);
}